// Round 8
// baseline (97.655 us; speedup 1.0000x reference)
//
#include <hip/hip_runtime.h>
#include <math.h>

// Match numpy f32 semantics bit-exactly in the binning chain: NO FMA contraction.
#pragma clang fp contract(off)

#define B_      2
#define L_      2048
#define K_      32
#define NBINS   37
#define H_      64
#define WD_ROWS 925   // 5*5*37
#define NRES    (B_ * L_)
#define CPB     4     // centers (b,l) per edge block

typedef unsigned short ushort_t;
typedef unsigned int   uint_t;

__device__ __forceinline__ float bits2f(uint_t u) {
  union { uint_t i; float f; } c; c.i = u; return c.f;
}
__device__ __forceinline__ ushort_t f2bf_rne(float f) {
  union { uint_t i; float f; } c; c.f = f;
  uint_t u = c.i;
  u += 0x7fffu + ((u >> 16) & 1u);
  return (ushort_t)(u >> 16);
}

// Correctly-rounded f32 sqrt (Figueroa: f64 sqrt then round == RN f32 sqrt).
__device__ __forceinline__ float sqrt_f32_exact(float s) {
  return (float)sqrt((double)s);
}

// v / max(||v||, 1e-12) in f32, numpy op order: ((x*x + y*y) + z*z)
__device__ __forceinline__ void norm3f(float& x, float& y, float& z) {
  float s = (x*x + y*y) + z*z;
  float n = sqrt_f32_exact(s);
  n = fmaxf(n, 1e-12f);
  x = x / n; y = y / n; z = z / n;
}

// Blocks 0..16   : peW[rel+32][h] = b_edge[h] + sum_j pe_j(rel)*W_pe[j][h] (65x64 f32)
// Blocks 17..32  : allc[res][0..14] = 5 atoms (N,CA,C,O,virtualCB), padded to 16 f32
// Blocks 33..264 : Wbf[r*64+h] = bf16(W_edge[r][h]) for r < 925  (118 KB gather table)
__global__ __launch_bounds__(256) void prep_kernel(
    const float* __restrict__ coords,   // (B,L,4,3) f32
    const float* __restrict__ W_edge,   // (989,64) f32
    const float* __restrict__ b_edge,   // (64,) f32
    float*       __restrict__ peW,      // (65,64) f32
    float*       __restrict__ allc,     // (NRES,16) f32
    ushort_t*    __restrict__ Wbf)      // (925,64) bf16
{
  const int t = threadIdx.x;
  if (blockIdx.x < 17) {
    __shared__ double pe[4][64];
    const int row = t >> 6;                 // 0..3
    const int r   = blockIdx.x * 4 + row;   // rel+32 in [0,65)
    const int h   = t & 63;
    if (r < 65 && h < 32) {
      const double c = -log(10000.0) / 64.0;
      const double ang = (double)(r - 32) * exp((double)(2 * h) * c);
      pe[row][2*h]     = sin(ang);
      pe[row][2*h + 1] = cos(ang);
    }
    __syncthreads();
    if (r < 65) {
      double acc = (double)b_edge[h];
      for (int j = 0; j < 64; ++j)
        acc += pe[row][j] * (double)W_edge[(WD_ROWS + j) * H_ + h];
      peW[r * H_ + h] = (float)acc;
    }
  } else if (blockIdx.x < 33) {
    const int res = (blockIdx.x - 17) * 256 + t;   // 0..NRES-1 exactly
    const float* cp = coords + (size_t)res * 12;
    float a[4][3];
    #pragma unroll
    for (int q = 0; q < 4; ++q)
      #pragma unroll
      for (int d = 0; d < 3; ++d)
        a[q][d] = cp[q * 3 + d];

    // ca_n = normalize(N - CA); ca_c = normalize(C - CA)   (f32, numpy order)
    float nx = a[0][0]-a[1][0], ny = a[0][1]-a[1][1], nz = a[0][2]-a[1][2];
    float cx = a[2][0]-a[1][0], cy = a[2][1]-a[1][1], cz = a[2][2]-a[1][2];
    norm3f(nx, ny, nz);
    norm3f(cx, cy, cz);
    float bx = nx + cx, by = ny + cy, bz = nz + cz;                    // bisector
    norm3f(bx, by, bz);
    float px = ny*cz - nz*cy, py = nz*cx - nx*cz, pz = nx*cy - ny*cx;  // perp
    norm3f(px, py, pz);
    float dx = -bx + 0.5f*px, dy = -by + 0.5f*py, dz = -bz + 0.5f*pz;  // cb_dir
    norm3f(dx, dy, dz);

    float row[16];
    #pragma unroll
    for (int q = 0; q < 4; ++q)
      #pragma unroll
      for (int d = 0; d < 3; ++d)
        row[q * 3 + d] = a[q][d];
    row[12] = a[1][0] + 1.54f * dx;
    row[13] = a[1][1] + 1.54f * dy;
    row[14] = a[1][2] + 1.54f * dz;
    row[15] = 0.0f;

    float4* o = (float4*)(allc + (size_t)res * 16);
    o[0] = make_float4(row[0],  row[1],  row[2],  row[3]);
    o[1] = make_float4(row[4],  row[5],  row[6],  row[7]);
    o[2] = make_float4(row[8],  row[9],  row[10], row[11]);
    o[3] = make_float4(row[12], row[13], row[14], row[15]);
  } else {
    const int e = (blockIdx.x - 33) * 256 + t;     // 0 .. 925*64-1
    if (e < WD_ROWS * H_) Wbf[e] = f2bf_rne(W_edge[e]);
  }
}

// One block = CPB centers, each with K=32 neighbors. Phase-B lane layout:
// i = t>>3 (item), sub = t&7; lane owns h in [8*sub, 8*sub+8); per item-row the
// gather is ONE uint4 load (8 lanes x 16 B = 128 B contiguous, 2 lines).
// The c-loop is kept sequential (unroll 1) to hold VGPR pressure at the R6
// level — R7 showed batching 25 offsets/loads into registers costs occupancy.
__global__ __launch_bounds__(256) void edge_kernel(
    const int*      __restrict__ nbr,   // (B,L,K) int32
    const float*    __restrict__ allc,  // (NRES,16) f32
    const ushort_t* __restrict__ Wbf,   // (925,64) bf16
    const float*    __restrict__ peW,   // (65,64) f32
    float*          __restrict__ out)   // (B,L,K,64) f32
{
  __shared__ float centers[CPB][16];
  __shared__ float natoms[CPB][K_][16];
  __shared__ int   woff[CPB][K_][25];   // element offset (p*37+bin)*64
  __shared__ int   relid[CPB][K_];

  const int t   = threadIdx.x;
  const int bl0 = blockIdx.x * CPB;     // first center (b*L_ + l); CPB | L_ so
                                        // a block never straddles the batch dim
  if (t < 4 * CPB) {
    const int c = t >> 2;
    ((float4*)centers[c])[t & 3] =
        ((const float4*)(allc + (size_t)(bl0 + c) * 16))[t & 3];
  }
  for (int u = t; u < CPB * K_ * 4; u += 256) {
    const int c = u >> 7, i = (u >> 2) & (K_ - 1), q = u & 3;
    const int bl = bl0 + c;
    const int nb = nbr[bl * K_ + i];
    const int brow = (bl & ~(L_ - 1)) + nb;   // b*L_ + nb
    ((float4*)natoms[c][i])[q] = ((const float4*)(allc + (size_t)brow * 16))[q];
    if (q == 0) {
      int rel = nb - (bl & (L_ - 1));
      rel = rel < -32 ? -32 : (rel > 32 ? 32 : rel);
      relid[c][i] = rel + 32;
    }
  }
  __syncthreads();

  // CPB*K*25 pair distances -> exact f32 searchsorted -> row offsets
  for (int task = t; task < CPB * K_ * 25; task += 256) {
    const int c   = task / (K_ * 25);
    const int rem = task - c * (K_ * 25);
    const int ii  = rem / 25;
    const int p   = rem - ii * 25;
    const int a1 = p / 5, a2 = p - a1 * 5;
    const float dx = centers[c][a1 * 3 + 0] - natoms[c][ii][a2 * 3 + 0];
    const float dy = centers[c][a1 * 3 + 1] - natoms[c][ii][a2 * 3 + 1];
    const float dz = centers[c][a1 * 3 + 2] - natoms[c][ii][a2 * 3 + 2];
    const float d2 = (dx*dx + dy*dy) + dz*dz;   // numpy add.reduce order
    const float d  = sqrt_f32_exact(d2);
    int m = (int)ceilf((d - 2.0f) * 2.0f);      // seed; fixups make it exact
    if (m < 0)  m = 0;
    if (m > NBINS) m = NBINS;
    while (m < NBINS && (2.0f + 0.5f * (float)m) < d) ++m;
    while (m > 0 && !((2.0f + 0.5f * (float)(m - 1)) < d)) --m;
    const int idx = m < (NBINS - 1) ? m : (NBINS - 1);
    woff[c][ii][p] = (p * NBINS + idx) * H_;
  }
  __syncthreads();

  // out[g][h] = peW[rel][h] + sum_p bf16(W_dist[row_p][h]),  h in [8*sub, ...)
  {
    const int i   = t >> 3;
    const int sub = t & 7;
    const int h0  = sub * 8;

    #pragma unroll 1
    for (int c = 0; c < CPB; ++c) {
      const int g = (bl0 + c) * K_ + i;

      const float* pw = peW + relid[c][i] * H_ + h0;
      const float4 p0 = *(const float4*)(pw);
      const float4 p1 = *(const float4*)(pw + 4);
      float acc[8] = {p0.x, p0.y, p0.z, p0.w, p1.x, p1.y, p1.z, p1.w};

      #pragma unroll 5
      for (int p = 0; p < 25; ++p) {
        const uint4 w = *(const uint4*)(Wbf + woff[c][i][p] + h0);  // 8 bf16
        acc[0] += bits2f(w.x << 16); acc[1] += bits2f(w.x & 0xffff0000u);
        acc[2] += bits2f(w.y << 16); acc[3] += bits2f(w.y & 0xffff0000u);
        acc[4] += bits2f(w.z << 16); acc[5] += bits2f(w.z & 0xffff0000u);
        acc[6] += bits2f(w.w << 16); acc[7] += bits2f(w.w & 0xffff0000u);
      }

      float* po = out + (size_t)g * H_ + h0;
      *(float4*)(po)     = make_float4(acc[0], acc[1], acc[2], acc[3]);
      *(float4*)(po + 4) = make_float4(acc[4], acc[5], acc[6], acc[7]);
    }
  }
}

extern "C" void kernel_launch(void* const* d_in, const int* in_sizes, int n_in,
                              void* d_out, int out_size, void* d_ws, size_t ws_size,
                              hipStream_t stream) {
  const float* coords = (const float*)d_in[0];
  const int*   nbr    = (const int*)d_in[1];
  const float* W      = (const float*)d_in[2];
  const float* bvec   = (const float*)d_in[3];
  float*       out    = (float*)d_out;
  float*       peW    = (float*)d_ws;                          // 16.6 KB
  ushort_t*    Wbf    = (ushort_t*)((char*)d_ws + 32768);      // 118.4 KB
  float*       allc   = (float*)((char*)d_ws + 163840);        // 262 KB

  prep_kernel<<<33 + (WD_ROWS * H_ + 255) / 256, 256, 0, stream>>>(
      coords, W, bvec, peW, allc, Wbf);
  edge_kernel<<<NRES / CPB, 256, 0, stream>>>(nbr, allc, Wbf, peW, out);
}

// Round 9
// 93.400 us; speedup vs baseline: 1.0456x; 1.0456x over previous
//
#include <hip/hip_runtime.h>
#include <math.h>

// Match numpy f32 semantics bit-exactly in the binning chain: NO FMA contraction.
#pragma clang fp contract(off)

#define B_      2
#define L_      2048
#define K_      32
#define NBINS   37
#define H_      64
#define WD_ROWS 925   // 5*5*37
#define NRES    (B_ * L_)

typedef unsigned short ushort_t;
typedef unsigned int   uint_t;

__device__ __forceinline__ float bits2f(uint_t u) {
  union { uint_t i; float f; } c; c.i = u; return c.f;
}
__device__ __forceinline__ ushort_t f2bf_rne(float f) {
  union { uint_t i; float f; } c; c.f = f;
  uint_t u = c.i;
  u += 0x7fffu + ((u >> 16) & 1u);
  return (ushort_t)(u >> 16);
}

// Correctly-rounded f32 sqrt (Figueroa: f64 sqrt then round == RN f32 sqrt).
__device__ __forceinline__ float sqrt_f32_exact(float s) {
  return (float)sqrt((double)s);
}

// v / max(||v||, 1e-12) in f32, numpy op order: ((x*x + y*y) + z*z)
__device__ __forceinline__ void norm3f(float& x, float& y, float& z) {
  float s = (x*x + y*y) + z*z;
  float n = sqrt_f32_exact(s);
  n = fmaxf(n, 1e-12f);
  x = x / n; y = y / n; z = z / n;
}

// Blocks 0..16   : peW[rel+32][h] = b_edge[h] + sum_j pe_j(rel)*W_pe[j][h] (65x64 f32)
// Blocks 17..32  : allc[res][0..14] = 5 atoms (N,CA,C,O,virtualCB), padded to 16 f32
// Blocks 33..264 : Wbf[r*64+h] = bf16(W_edge[r][h]) for r < 925  (118 KB gather table)
__global__ __launch_bounds__(256) void prep_kernel(
    const float* __restrict__ coords,   // (B,L,4,3) f32
    const float* __restrict__ W_edge,   // (989,64) f32
    const float* __restrict__ b_edge,   // (64,) f32
    float*       __restrict__ peW,      // (65,64) f32
    float*       __restrict__ allc,     // (NRES,16) f32
    ushort_t*    __restrict__ Wbf)      // (925,64) bf16
{
  const int t = threadIdx.x;
  if (blockIdx.x < 17) {
    __shared__ double pe[4][64];
    const int row = t >> 6;                 // 0..3
    const int r   = blockIdx.x * 4 + row;   // rel+32 in [0,65)
    const int h   = t & 63;
    if (r < 65 && h < 32) {
      const double c = -log(10000.0) / 64.0;
      const double ang = (double)(r - 32) * exp((double)(2 * h) * c);
      pe[row][2*h]     = sin(ang);
      pe[row][2*h + 1] = cos(ang);
    }
    __syncthreads();
    if (r < 65) {
      double acc = (double)b_edge[h];
      for (int j = 0; j < 64; ++j)
        acc += pe[row][j] * (double)W_edge[(WD_ROWS + j) * H_ + h];
      peW[r * H_ + h] = (float)acc;
    }
  } else if (blockIdx.x < 33) {
    const int res = (blockIdx.x - 17) * 256 + t;   // 0..NRES-1 exactly
    const float* cp = coords + (size_t)res * 12;
    float a[4][3];
    #pragma unroll
    for (int q = 0; q < 4; ++q)
      #pragma unroll
      for (int d = 0; d < 3; ++d)
        a[q][d] = cp[q * 3 + d];

    // ca_n = normalize(N - CA); ca_c = normalize(C - CA)   (f32, numpy order)
    float nx = a[0][0]-a[1][0], ny = a[0][1]-a[1][1], nz = a[0][2]-a[1][2];
    float cx = a[2][0]-a[1][0], cy = a[2][1]-a[1][1], cz = a[2][2]-a[1][2];
    norm3f(nx, ny, nz);
    norm3f(cx, cy, cz);
    float bx = nx + cx, by = ny + cy, bz = nz + cz;                    // bisector
    norm3f(bx, by, bz);
    float px = ny*cz - nz*cy, py = nz*cx - nx*cz, pz = nx*cy - ny*cx;  // perp
    norm3f(px, py, pz);
    float dx = -bx + 0.5f*px, dy = -by + 0.5f*py, dz = -bz + 0.5f*pz;  // cb_dir
    norm3f(dx, dy, dz);

    float row[16];
    #pragma unroll
    for (int q = 0; q < 4; ++q)
      #pragma unroll
      for (int d = 0; d < 3; ++d)
        row[q * 3 + d] = a[q][d];
    row[12] = a[1][0] + 1.54f * dx;
    row[13] = a[1][1] + 1.54f * dy;
    row[14] = a[1][2] + 1.54f * dz;
    row[15] = 0.0f;

    float4* o = (float4*)(allc + (size_t)res * 16);
    o[0] = make_float4(row[0],  row[1],  row[2],  row[3]);
    o[1] = make_float4(row[4],  row[5],  row[6],  row[7]);
    o[2] = make_float4(row[8],  row[9],  row[10], row[11]);
    o[3] = make_float4(row[12], row[13], row[14], row[15]);
  } else {
    const int e = (blockIdx.x - 33) * 256 + t;     // 0 .. 925*64-1
    if (e < WD_ROWS * H_) Wbf[e] = f2bf_rne(W_edge[e]);
  }
}

// One block = one (b,l) center with its K=32 neighbors.
// Phase-B lane layout: i = t>>3 (item), sub = t&7; lane owns h in [8*sub, 8*sub+8).
// Per item-row gather = ONE uint4 load (8 lanes x 16 B = 128 B contiguous, 2 lines).
// NOTE (R7/R8 post-mortems): keep unroll 5 + one center per block. Batching 25
// offsets/loads into VGPRs (R7) or 4 centers/block (R8) both cost ~4 us via
// occupancy / inter-block-overlap loss. This structure is the local optimum.
__global__ __launch_bounds__(256) void edge_kernel(
    const int*      __restrict__ nbr,   // (B,L,K) int32
    const float*    __restrict__ allc,  // (NRES,16) f32
    const ushort_t* __restrict__ Wbf,   // (925,64) bf16
    const float*    __restrict__ peW,   // (65,64) f32
    float*          __restrict__ out)   // (B,L,K,64) f32
{
  __shared__ float center[16];
  __shared__ float natoms[K_][16];
  __shared__ int   woff[K_][25];        // element offset (p*37+bin)*64
  __shared__ int   relid[K_];

  const int t  = threadIdx.x;
  const int bl = blockIdx.x;            // b*L_ + l
  const int l  = bl & (L_ - 1);
  const int g0 = bl * K_;

  if (t < 4) {
    ((float4*)center)[t] = ((const float4*)(allc + (size_t)bl * 16))[t];
  }
  if (t < 4 * K_) {
    const int i = t >> 2, c = t & 3;
    const int nb = nbr[g0 + i];
    const int brow = (bl & ~(L_ - 1)) + nb;   // b*L_ + nb
    ((float4*)natoms[i])[c] = ((const float4*)(allc + (size_t)brow * 16))[c];
    if (c == 0) {
      int rel = nb - l;
      rel = rel < -32 ? -32 : (rel > 32 ? 32 : rel);
      relid[i] = rel + 32;
    }
  }
  __syncthreads();

  // 25 pair distances per item -> exact f32 searchsorted -> row offsets
  for (int task = t; task < K_ * 25; task += 256) {
    const int i  = task / 25;
    const int p  = task - i * 25;
    const int a1 = p / 5, a2 = p - a1 * 5;
    const float dx = center[a1 * 3 + 0] - natoms[i][a2 * 3 + 0];
    const float dy = center[a1 * 3 + 1] - natoms[i][a2 * 3 + 1];
    const float dz = center[a1 * 3 + 2] - natoms[i][a2 * 3 + 2];
    const float d2 = (dx*dx + dy*dy) + dz*dz;   // numpy add.reduce order
    const float d  = sqrt_f32_exact(d2);
    int m = (int)ceilf((d - 2.0f) * 2.0f);      // seed; fixups make it exact
    if (m < 0)  m = 0;
    if (m > NBINS) m = NBINS;
    while (m < NBINS && (2.0f + 0.5f * (float)m) < d) ++m;
    while (m > 0 && !((2.0f + 0.5f * (float)(m - 1)) < d)) --m;
    const int idx = m < (NBINS - 1) ? m : (NBINS - 1);
    woff[i][p] = (p * NBINS + idx) * H_;
  }
  __syncthreads();

  // out[g][h] = peW[rel][h] + sum_p bf16(W_dist[row_p][h]),  h in [8*sub, 8*sub+8)
  {
    const int i   = t >> 3;
    const int sub = t & 7;
    const int h0  = sub * 8;
    const int g   = g0 + i;

    const float* pw = peW + relid[i] * H_ + h0;
    const float4 p0 = *(const float4*)(pw);
    const float4 p1 = *(const float4*)(pw + 4);
    float acc[8] = {p0.x, p0.y, p0.z, p0.w, p1.x, p1.y, p1.z, p1.w};

    #pragma unroll 5
    for (int p = 0; p < 25; ++p) {
      const uint4 w = *(const uint4*)(Wbf + woff[i][p] + h0);  // 8 bf16, contiguous
      acc[0] += bits2f(w.x << 16); acc[1] += bits2f(w.x & 0xffff0000u);
      acc[2] += bits2f(w.y << 16); acc[3] += bits2f(w.y & 0xffff0000u);
      acc[4] += bits2f(w.z << 16); acc[5] += bits2f(w.z & 0xffff0000u);
      acc[6] += bits2f(w.w << 16); acc[7] += bits2f(w.w & 0xffff0000u);
    }

    float* po = out + (size_t)g * H_ + h0;
    *(float4*)(po)     = make_float4(acc[0], acc[1], acc[2], acc[3]);
    *(float4*)(po + 4) = make_float4(acc[4], acc[5], acc[6], acc[7]);
  }
}

extern "C" void kernel_launch(void* const* d_in, const int* in_sizes, int n_in,
                              void* d_out, int out_size, void* d_ws, size_t ws_size,
                              hipStream_t stream) {
  const float* coords = (const float*)d_in[0];
  const int*   nbr    = (const int*)d_in[1];
  const float* W      = (const float*)d_in[2];
  const float* bvec   = (const float*)d_in[3];
  float*       out    = (float*)d_out;
  float*       peW    = (float*)d_ws;                          // 16.6 KB
  ushort_t*    Wbf    = (ushort_t*)((char*)d_ws + 32768);      // 118.4 KB
  float*       allc   = (float*)((char*)d_ws + 163840);        // 262 KB

  prep_kernel<<<33 + (WD_ROWS * H_ + 255) / 256, 256, 0, stream>>>(
      coords, W, bvec, peW, allc, Wbf);
  edge_kernel<<<NRES, 256, 0, stream>>>(nbr, allc, Wbf, peW, out);
}